// Round 9
// baseline (406.093 us; speedup 1.0000x reference)
//
#include <hip/hip_runtime.h>

// Problem constants (fixed by the reference)
#define NB    2
#define LQT   12096      // query tokens per batch
#define LINT  2304       // feat tokens per batch (48*48)
#define DIMC  768
#define NHD   6
#define NPT   4
#define DHD   128
#define HIDC  192
#define HH    48
#define WW    48

typedef __attribute__((ext_vector_type(8))) short bf16x8;
typedef __attribute__((ext_vector_type(4))) float f32x4;

__device__ __forceinline__ unsigned short f2bf(float f) {
  unsigned int u = __builtin_bit_cast(unsigned int, f);
  u += 0x7FFFu + ((u >> 16) & 1u);   // round-to-nearest-even
  return (unsigned short)(u >> 16);
}
__device__ __forceinline__ float bf2f(unsigned short h) {
  unsigned int u = ((unsigned int)h) << 16;
  return __builtin_bit_cast(float, u);
}

// global -> LDS direct copy, 16B per lane. LDS base must be wave-uniform+lane*16.
__device__ __forceinline__ void gload16(const unsigned short* g, unsigned short* l) {
  __builtin_amdgcn_global_load_lds(
      (const __attribute__((address_space(1))) unsigned int*)g,
      (__attribute__((address_space(3))) unsigned int*)l, 16, 0, 0);
}

// ---------------- weight packing: transpose [K][N]->bf16 [rows>=N][K], pad rows with 0
__global__ __launch_bounds__(256) void pack_wt(const float* __restrict__ src,
                                               unsigned short* __restrict__ dst,
                                               int K, int N, int rows) {
  size_t i = (size_t)blockIdx.x * 256 + threadIdx.x;
  if (i >= (size_t)rows * K) return;
  int n = (int)(i / K), k = (int)(i % K);
  float v = (n < N) ? src[(size_t)k * N + n] : 0.f;
  dst[i] = f2bf(v);
}

// fused sampling-offset (48 cols) + attn-weight (24 cols) weight pack into [144][768]
__global__ __launch_bounds__(256) void pack_soaw(const float* __restrict__ soW,
                                                 const float* __restrict__ awW,
                                                 const float* __restrict__ sob,
                                                 const float* __restrict__ awb,
                                                 unsigned short* __restrict__ dst,
                                                 float* __restrict__ bdst) {
  size_t i = (size_t)blockIdx.x * 256 + threadIdx.x;
  if (i < 144) bdst[i] = (i < 48) ? sob[i] : (i < 72 ? awb[i - 48] : 0.f);
  if (i >= (size_t)144 * DIMC) return;
  int n = (int)(i / DIMC), k = (int)(i % DIMC);
  float v = (n < 48) ? soW[(size_t)k * 48 + n]
                     : (n < 72 ? awW[(size_t)k * 24 + (n - 48)] : 0.f);
  dst[i] = f2bf(v);
}

// ---------------- LayerNorm (eps=1e-6), templated input dtype, -> bf16
template <bool IN_BF16>
__global__ __launch_bounds__(256) void ln_to_bf16(const void* __restrict__ in_,
                                                  const float* __restrict__ gamma,
                                                  const float* __restrict__ beta,
                                                  unsigned short* __restrict__ out) {
  const int row = blockIdx.x;
  const int t = threadIdx.x;
  float v0, v1, v2;
  if (IN_BF16) {
    const unsigned short* x = (const unsigned short*)in_ + (size_t)row * DIMC;
    v0 = bf2f(x[t]); v1 = bf2f(x[t + 256]); v2 = bf2f(x[t + 512]);
  } else {
    const float* x = (const float*)in_ + (size_t)row * DIMC;
    v0 = x[t]; v1 = x[t + 256]; v2 = x[t + 512];
  }
  float s = v0 + v1 + v2;
  float s2 = v0 * v0 + v1 * v1 + v2 * v2;
#pragma unroll
  for (int o = 32; o > 0; o >>= 1) {
    s += __shfl_down(s, o);
    s2 += __shfl_down(s2, o);
  }
  __shared__ float red[8];
  const int wave = t >> 6, lane = t & 63;
  if (lane == 0) { red[wave] = s; red[wave + 4] = s2; }
  __syncthreads();
  float S = red[0] + red[1] + red[2] + red[3];
  float S2 = red[4] + red[5] + red[6] + red[7];
  float mean = S * (1.0f / DIMC);
  float var = S2 * (1.0f / DIMC) - mean * mean;
  float inv = rsqrtf(var + 1e-6f);
  unsigned short* o0 = out + (size_t)row * DIMC;
  o0[t]       = f2bf((v0 - mean) * inv * gamma[t]       + beta[t]);
  o0[t + 256] = f2bf((v1 - mean) * inv * gamma[t + 256] + beta[t + 256]);
  o0[t + 512] = f2bf((v2 - mean) * inv * gamma[t + 512] + beta[t + 512]);
}

// ---------------- weights-stationary MFMA GEMM: C[M][N] = A[M][K]*Bt[N][K]^T + bias (+add)
// B-panel (48 cols x full K, bf16) staged into LDS ONCE per block (one barrier),
// then each wave independently streams its own 32 A-rows global->registers and
// MFMAs against the resident panel. NO barriers in the K-loop: waves free-run,
// latency hidden by 2-deep A prefetch + wave drift. LDS slot-XOR swizzle
// slot^(row&7) applied on stage source AND ds_read (rule #21) -> 8x16B position
// spread (same 0-conflict structure as the measured R4 layout).
// MW = m-waves per block (block = MW*64 threads, BM = MW*32 rows).
// A buffers must have ceil(M/BM) rows allocated; epilogue guards m<M, n<N.
template <int KT, int MW, bool HAS_ADD, bool ADD_BF16, bool OUT_BF16>
__global__ __launch_bounds__(MW * 64) void gemm_ws(const unsigned short* __restrict__ A,
                                                   const unsigned short* __restrict__ Bt,
                                                   const float* __restrict__ bias,
                                                   const void* __restrict__ add_,
                                                   void* __restrict__ out_,
                                                   int M, int N, int nn) {
  constexpr int SLOTS = KT / 8;        // 16B slots per panel row
  constexpr int NT = KT / 32;          // K-steps
  constexpr int CH = 48 * SLOTS;       // total 16B chunks in panel
  constexpr int NTHR = MW * 64;
  __shared__ unsigned short Bp[48 * KT];
  const int t = threadIdx.x;
  const int wave = t >> 6, lane = t & 63;
  const int lr = lane & 15, lg = lane >> 4;

  // bijective XCD-chunked swizzle (m204); n-fastest so same-m blocks share L2
  const int nwg = gridDim.x;
  const int qq = nwg >> 3, rr = nwg & 7;
  const int xcd = blockIdx.x & 7, pos = blockIdx.x >> 3;
  const int swz = ((xcd < rr) ? xcd * (qq + 1) : rr * (qq + 1) + (xcd - rr) * qq) + pos;
  const int m0 = (swz / nn) * (MW * 32);
  const int n0 = (swz % nn) * 48;

  // stage B panel [48][KT] linear in LDS, source slot pre-XOR-swizzled
#pragma unroll
  for (int i = 0; i < (CH + NTHR - 1) / NTHR; ++i) {
    const int c = t + i * NTHR;
    if ((CH % NTHR == 0) || c < CH) {
      const int row = c / SLOTS, slot = c % SLOTS;
      const int ca = slot ^ (row & 7);
      gload16(Bt + (size_t)(n0 + row) * KT + ca * 8, &Bp[c * 8]);
    }
  }
  asm volatile("s_waitcnt vmcnt(0)" ::: "memory");
  __syncthreads();

  // wave-private A stream: rows m0+wave*32 + {lr, 16+lr}
  const unsigned short* ap = A + (size_t)(m0 + wave * 32 + lr) * KT + lg * 8;
  const size_t a16 = (size_t)16 * KT;

  bf16x8 a0 = *(const bf16x8*)(ap);
  bf16x8 a1 = *(const bf16x8*)(ap + a16);
  f32x4 acc[2][3] = {};

#pragma unroll 6
  for (int kt = 0; kt < NT; ++kt) {
    const bf16x8 c0 = a0, c1 = a1;
    if (kt + 1 < NT) {                       // 2-deep prefetch of next A frags
      a0 = *(const bf16x8*)(ap + (kt + 1) * 32);
      a1 = *(const bf16x8*)(ap + a16 + (kt + 1) * 32);
    }
    bf16x8 bg[3];
#pragma unroll
    for (int j = 0; j < 3; ++j) {
      const int prow = j * 16 + lr;
      const int s = (kt * 4 + lg) ^ (prow & 7);
      bg[j] = *(const bf16x8*)(&Bp[prow * KT + s * 8]);
    }
#pragma unroll
    for (int j = 0; j < 3; ++j) {
      acc[0][j] = __builtin_amdgcn_mfma_f32_16x16x32_bf16(c0, bg[j], acc[0][j], 0, 0, 0);
      acc[1][j] = __builtin_amdgcn_mfma_f32_16x16x32_bf16(c1, bg[j], acc[1][j], 0, 0, 0);
    }
  }

  const float* addf = (const float*)add_;
  const unsigned short* addb = (const unsigned short*)add_;
  float* outf = (float*)out_;
  unsigned short* outb = (unsigned short*)out_;
#pragma unroll
  for (int u = 0; u < 2; ++u) {
#pragma unroll
    for (int j = 0; j < 3; ++j) {
      const int n = n0 + j * 16 + lr;
      if (n < N) {
#pragma unroll
        for (int r = 0; r < 4; ++r) {
          const int m = m0 + wave * 32 + u * 16 + lg * 4 + r;
          if (m < M) {
            float v = acc[u][j][r] + bias[n];
            if (HAS_ADD) v += ADD_BF16 ? bf2f(addb[(size_t)m * N + n]) : addf[(size_t)m * N + n];
            if (OUT_BF16) outb[(size_t)m * N + n] = f2bf(v);
            else          outf[(size_t)m * N + n] = v;
          }
        }
      }
    }
  }
}

// ---------------- deformable sampling: softmax(attw) + bilinear gather + NP-sum
__global__ __launch_bounds__(192) void deform_attn(const float* __restrict__ soaw,
                                                   const float* __restrict__ rp,
                                                   const float* __restrict__ value,
                                                   unsigned short* __restrict__ attn) {
  const int row = blockIdx.x;  // b*LQT + q
  const int b = row / LQT;
  const int t = threadIdx.x;
  const int h = t >> 5;
  const int l = t & 31;
  const float* sa = soaw + (size_t)row * 128;
  const float bx = rp[(size_t)row * 2 + 0] * (float)WW - 0.5f;
  const float by = rp[(size_t)row * 2 + 1] * (float)HH - 0.5f;

  float lg0 = sa[48 + h * 4 + 0], lg1 = sa[48 + h * 4 + 1];
  float lg2 = sa[48 + h * 4 + 2], lg3 = sa[48 + h * 4 + 3];
  float mx = fmaxf(fmaxf(lg0, lg1), fmaxf(lg2, lg3));
  float e0 = expf(lg0 - mx), e1 = expf(lg1 - mx), e2 = expf(lg2 - mx), e3 = expf(lg3 - mx);
  float inv = 1.0f / (e0 + e1 + e2 + e3);
  float awp[4] = {e0 * inv, e1 * inv, e2 * inv, e3 * inv};

  const float* vb = value + (size_t)b * LINT * DIMC + h * DHD + l * 4;
  float ax = 0.f, ay = 0.f, az = 0.f, aw = 0.f;
#pragma unroll
  for (int p = 0; p < 4; ++p) {
    float fx = bx + sa[h * 8 + p * 2 + 0];
    float fy = by + sa[h * 8 + p * 2 + 1];
    float x0f = floorf(fx), y0f = floorf(fy);
    float wx = fx - x0f, wy = fy - y0f;
    int x0 = (int)x0f, y0 = (int)y0f;
#pragma unroll
    for (int dy = 0; dy < 2; ++dy) {
#pragma unroll
      for (int dx = 0; dx < 2; ++dx) {
        int xi = x0 + dx, yi = y0 + dy;
        float w = (dy ? wy : 1.f - wy) * (dx ? wx : 1.f - wx) * awp[p];
        if (xi < 0 || xi >= WW || yi < 0 || yi >= HH) w = 0.f;
        int xc = min(max(xi, 0), WW - 1), yc = min(max(yi, 0), HH - 1);
        const float4 g = *(const float4*)(vb + (size_t)(yc * WW + xc) * DIMC);
        ax += w * g.x; ay += w * g.y; az += w * g.z; aw += w * g.w;
      }
    }
  }
  unsigned short* op = attn + (size_t)row * DIMC + h * DHD + l * 4;
  ushort4 ov;
  ov.x = f2bf(ax); ov.y = f2bf(ay); ov.z = f2bf(az); ov.w = f2bf(aw);
  *(ushort4*)op = ov;
}

// ---------------- depthwise 3x3 conv (3 image scales) + exact GELU, bf16 in/out
__global__ __launch_bounds__(192) void dwconv_gelu(const unsigned short* __restrict__ h1,
                                                   const float* __restrict__ dwW,
                                                   const float* __restrict__ dwb,
                                                   unsigned short* __restrict__ out) {
  const int blk = blockIdx.x;  // b*LQT + q
  const int b = blk / LQT;
  const int q = blk % LQT;
  int base, Wi, Hi;
  if (q < 9216)       { base = 0;     Wi = 96; Hi = 96; }
  else if (q < 11520) { base = 9216;  Wi = 48; Hi = 48; }
  else                { base = 11520; Wi = 24; Hi = 24; }
  const int loc = q - base;
  const int y = loc / Wi, x = loc % Wi;
  const int c = threadIdx.x;
  const unsigned short* src = h1 + ((size_t)b * LQT + base) * HIDC + c;
  float acc = dwb[c];
#pragma unroll
  for (int dy = -1; dy <= 1; ++dy) {
    int yy = y + dy;
    if (yy < 0 || yy >= Hi) continue;
#pragma unroll
    for (int dx = -1; dx <= 1; ++dx) {
      int xx = x + dx;
      if (xx < 0 || xx >= Wi) continue;
      acc += dwW[c * 9 + (dy + 1) * 3 + (dx + 1)] * bf2f(src[(size_t)(yy * Wi + xx) * HIDC]);
    }
  }
  float g = 0.5f * acc * (1.0f + erff(acc * 0.70710678118654752f));
  out[(size_t)blk * HIDC + c] = f2bf(g);
}

// ---------------- launch
extern "C" void kernel_launch(void* const* d_in, const int* in_sizes, int n_in,
                              void* d_out, int out_size, void* d_ws, size_t ws_size,
                              hipStream_t stream) {
  const float* query = (const float*)d_in[0];
  const float* rp    = (const float*)d_in[1];
  const float* feat  = (const float*)d_in[2];
  const float* qn_g  = (const float*)d_in[7];
  const float* qn_b  = (const float*)d_in[8];
  const float* fn_g  = (const float*)d_in[9];
  const float* fn_b  = (const float*)d_in[10];
  const float* mn_g  = (const float*)d_in[11];
  const float* mn_b  = (const float*)d_in[12];
  const float* vW    = (const float*)d_in[13];
  const float* vb    = (const float*)d_in[14];
  const float* soW   = (const float*)d_in[15];
  const float* sob   = (const float*)d_in[16];
  const float* awW   = (const float*)d_in[17];
  const float* awb   = (const float*)d_in[18];
  const float* opW   = (const float*)d_in[19];
  const float* opb   = (const float*)d_in[20];
  const float* fc1W  = (const float*)d_in[21];
  const float* fc1b  = (const float*)d_in[22];
  const float* dwW   = (const float*)d_in[23];
  const float* dwb   = (const float*)d_in[24];
  const float* fc2W  = (const float*)d_in[25];
  const float* fc2b  = (const float*)d_in[26];
  float* out = (float*)d_out;
  (void)in_sizes; (void)n_in; (void)out_size; (void)ws_size;

  char* ws = (char*)d_ws;
  size_t off = 0;
  auto alloc = [&](size_t bytes) -> void* {
    off = (off + 255) & ~(size_t)255;
    void* p = ws + off;
    off += bytes;
    return p;
  };

  const int MQ = NB * LQT;    // 24192
  const int MQP = 24320;      // MQ rounded up to 256 (pad rows for BM=256 A-streams)
  const int MF = NB * LINT;   // 4608

  unsigned short* vWt    = (unsigned short*)alloc((size_t)768 * 768 * 2);
  unsigned short* opWt   = (unsigned short*)alloc((size_t)768 * 768 * 2);
  unsigned short* soawWt = (unsigned short*)alloc((size_t)144 * 768 * 2);
  unsigned short* fc1Wt  = (unsigned short*)alloc((size_t)192 * 768 * 2);
  unsigned short* fc2Wt  = (unsigned short*)alloc((size_t)768 * 192 * 2);
  float*          soawb  = (float*)alloc(144 * 4);
  unsigned short* f_ln   = (unsigned short*)alloc((size_t)MF * DIMC * 2);
  unsigned short* q_ln   = (unsigned short*)alloc((size_t)MQ * DIMC * 2);  // reused as ln(x)
  float*          value  = (float*)alloc((size_t)MF * DIMC * 4);
  float*          soaw   = (float*)alloc((size_t)MQP * 128 * 4);           // reused as conv out (bf16, padded rows)
  unsigned short* attnb  = (unsigned short*)alloc((size_t)MQP * DIMC * 2); // padded rows; reused as h1 (bf16)
  unsigned short* xbuf   = (unsigned short*)alloc((size_t)MQ * DIMC * 2);  // x residual in bf16

  unsigned short* h1b = attnb;                   // fc1 output (bf16), after attnb consumed
  unsigned short* coutb = (unsigned short*)soaw; // MQP*192*2 = 9.3MB < 12.4MB
  unsigned short* lnx = q_ln;

  // weight packing (tiny)
  pack_wt<<<dim3((768 * 768 + 255) / 256), dim3(256), 0, stream>>>(vW, vWt, 768, 768, 768);
  pack_wt<<<dim3((768 * 768 + 255) / 256), dim3(256), 0, stream>>>(opW, opWt, 768, 768, 768);
  pack_wt<<<dim3((192 * 768 + 255) / 256), dim3(256), 0, stream>>>(fc1W, fc1Wt, 768, 192, 192);
  pack_wt<<<dim3((768 * 192 + 255) / 256), dim3(256), 0, stream>>>(fc2W, fc2Wt, 192, 768, 768);
  pack_soaw<<<dim3((144 * 768 + 255) / 256), dim3(256), 0, stream>>>(soW, awW, sob, awb, soawWt, soawb);

  // LayerNorms (fp32 in)
  ln_to_bf16<false><<<dim3(MF), dim3(256), 0, stream>>>(feat, fn_g, fn_b, f_ln);
  ln_to_bf16<false><<<dim3(MQ), dim3(256), 0, stream>>>(query, qn_g, qn_b, q_ln);

  // value projection: [4608,768] = f_ln @ vW + vb   (BM=128, 36x16 blocks)
  gemm_ws<768, 4, false, false, false><<<dim3((MF / 128) * 16), dim3(256), 0, stream>>>(
      f_ln, vWt, vb, nullptr, value, MF, 768, 16);

  // sampling offsets + attn logits (N=128, panel padded to 144; BM=128, 189x3)
  gemm_ws<768, 4, false, false, false><<<dim3((MQ / 128) * 3), dim3(256), 0, stream>>>(
      q_ln, soawWt, soawb, nullptr, soaw, MQ, 128, 3);

  // deformable bilinear sampling -> attn operand (bf16)
  deform_attn<<<dim3(MQ), dim3(192), 0, stream>>>(soaw, rp, value, attnb);

  // output projection + residual: x = attn @ opW + opb + query  (BM=256, 95x16, bf16 out)
  gemm_ws<768, 8, true, false, true><<<dim3((MQP / 256) * 16), dim3(512), 0, stream>>>(
      attnb, opWt, opb, query, xbuf, MQ, 768, 16);

  // LN(x) (bf16 in)
  ln_to_bf16<true><<<dim3(MQ), dim3(256), 0, stream>>>(xbuf, mn_g, mn_b, lnx);

  // fc1: h1 = lnx @ fc1W + fc1b  (BM=128, 189x4, bf16 out)
  gemm_ws<768, 4, false, false, true><<<dim3((MQ / 128) * 4), dim3(256), 0, stream>>>(
      lnx, fc1Wt, fc1b, nullptr, h1b, MQ, 192, 4);

  // depthwise conv (3 scales) + GELU (bf16 in/out)
  dwconv_gelu<<<dim3(MQ), dim3(192), 0, stream>>>(h1b, dwW, dwb, coutb);

  // fc2 + residual: out = x + cout @ fc2W + fc2b  (K=192, BM=256, 95x16)
  gemm_ws<192, 8, true, true, false><<<dim3((MQP / 256) * 16), dim3(512), 0, stream>>>(
      coutb, fc2Wt, fc2b, xbuf, out, MQ, 768, 16);
}

// Round 10
// 350.485 us; speedup vs baseline: 1.1587x; 1.1587x over previous
//
#include <hip/hip_runtime.h>

// Problem constants (fixed by the reference)
#define NB    2
#define LQT   12096      // query tokens per batch
#define LINT  2304       // feat tokens per batch (48*48)
#define DIMC  768
#define NHD   6
#define NPT   4
#define DHD   128
#define HIDC  192
#define HH    48
#define WW    48

typedef __attribute__((ext_vector_type(8))) short bf16x8;
typedef __attribute__((ext_vector_type(4))) float f32x4;

__device__ __forceinline__ unsigned short f2bf(float f) {
  unsigned int u = __builtin_bit_cast(unsigned int, f);
  u += 0x7FFFu + ((u >> 16) & 1u);   // round-to-nearest-even
  return (unsigned short)(u >> 16);
}
__device__ __forceinline__ float bf2f(unsigned short h) {
  unsigned int u = ((unsigned int)h) << 16;
  return __builtin_bit_cast(float, u);
}

// global -> LDS direct copy, 16B per lane. LDS dest = wave-uniform + lane*16.
__device__ __forceinline__ void gload16(const unsigned short* g, unsigned short* l) {
  __builtin_amdgcn_global_load_lds(
      (const __attribute__((address_space(1))) unsigned int*)g,
      (__attribute__((address_space(3))) unsigned int*)l, 16, 0, 0);
}

// ---------------- weight packing: transpose [K][N]->bf16 [rows>=N][K], pad rows with 0
__global__ __launch_bounds__(256) void pack_wt(const float* __restrict__ src,
                                               unsigned short* __restrict__ dst,
                                               int K, int N, int rows) {
  size_t i = (size_t)blockIdx.x * 256 + threadIdx.x;
  if (i >= (size_t)rows * K) return;
  int n = (int)(i / K), k = (int)(i % K);
  float v = (n < N) ? src[(size_t)k * N + n] : 0.f;
  dst[i] = f2bf(v);
}

// fused sampling-offset (48 cols) + attn-weight (24 cols) weight pack into [128][768]
__global__ __launch_bounds__(256) void pack_soaw(const float* __restrict__ soW,
                                                 const float* __restrict__ awW,
                                                 const float* __restrict__ sob,
                                                 const float* __restrict__ awb,
                                                 unsigned short* __restrict__ dst,
                                                 float* __restrict__ bdst) {
  size_t i = (size_t)blockIdx.x * 256 + threadIdx.x;
  if (i < 128) bdst[i] = (i < 48) ? sob[i] : (i < 72 ? awb[i - 48] : 0.f);
  if (i >= (size_t)128 * DIMC) return;
  int n = (int)(i / DIMC), k = (int)(i % DIMC);
  float v = (n < 48) ? soW[(size_t)k * 48 + n]
                     : (n < 72 ? awW[(size_t)k * 24 + (n - 48)] : 0.f);
  dst[i] = f2bf(v);
}

// ---------------- LayerNorm (eps=1e-6), templated input dtype, -> bf16
template <bool IN_BF16>
__global__ __launch_bounds__(256) void ln_to_bf16(const void* __restrict__ in_,
                                                  const float* __restrict__ gamma,
                                                  const float* __restrict__ beta,
                                                  unsigned short* __restrict__ out) {
  const int row = blockIdx.x;
  const int t = threadIdx.x;
  float v0, v1, v2;
  if (IN_BF16) {
    const unsigned short* x = (const unsigned short*)in_ + (size_t)row * DIMC;
    v0 = bf2f(x[t]); v1 = bf2f(x[t + 256]); v2 = bf2f(x[t + 512]);
  } else {
    const float* x = (const float*)in_ + (size_t)row * DIMC;
    v0 = x[t]; v1 = x[t + 256]; v2 = x[t + 512];
  }
  float s = v0 + v1 + v2;
  float s2 = v0 * v0 + v1 * v1 + v2 * v2;
#pragma unroll
  for (int o = 32; o > 0; o >>= 1) {
    s += __shfl_down(s, o);
    s2 += __shfl_down(s2, o);
  }
  __shared__ float red[8];
  const int wave = t >> 6, lane = t & 63;
  if (lane == 0) { red[wave] = s; red[wave + 4] = s2; }
  __syncthreads();
  float S = red[0] + red[1] + red[2] + red[3];
  float S2 = red[4] + red[5] + red[6] + red[7];
  float mean = S * (1.0f / DIMC);
  float var = S2 * (1.0f / DIMC) - mean * mean;
  float inv = rsqrtf(var + 1e-6f);
  unsigned short* o0 = out + (size_t)row * DIMC;
  o0[t]       = f2bf((v0 - mean) * inv * gamma[t]       + beta[t]);
  o0[t + 256] = f2bf((v1 - mean) * inv * gamma[t + 256] + beta[t + 256]);
  o0[t + 512] = f2bf((v2 - mean) * inv * gamma[t + 512] + beta[t + 512]);
}

// ---------------- LDS-pipelined MFMA GEMM (R3-proven structure, dtype-templated)
// Tile BM=2*WM*16 x BN=2*WN*16, BK=64, 4 waves (2x2). Double-buffered LDS,
// 2-phase: stage(next) -> ds_read+MFMA(cur) -> __syncthreads(). XOR slot^(row&7)
// on BOTH global source chunk and ds_read slot (rule #21; measured 0 conflicts).
// 1-D grid, n-fastest, bijective XCD-chunked swizzle (m204). K % 64 == 0.
template <int WM, int WN, bool HAS_ADD, bool ADD_BF16, bool OUT_BF16>
__global__ __launch_bounds__(256) void gemm_bt(const unsigned short* __restrict__ A,
                                               const unsigned short* __restrict__ Bt,
                                               const float* __restrict__ bias,
                                               const void* __restrict__ add_,
                                               void* __restrict__ out_,
                                               int M, int N, int K, int nn) {
  constexpr int BM = 2 * WM * 16;
  constexpr int BN = 2 * WN * 16;
  constexpr int CHA = BM * 8;               // A 16B-chunks per buffer
  constexpr int CHT = (BM + BN) * 8;        // total chunks per buffer
  __shared__ unsigned short As[2][BM * 64];
  __shared__ unsigned short Bs[2][BN * 64];
  const int t = threadIdx.x;
  const int wave = t >> 6, lane = t & 63;

  const int nwg = gridDim.x;
  const int qq = nwg >> 3, rr = nwg & 7;
  const int xcd = blockIdx.x & 7, pos = blockIdx.x >> 3;
  const int swz = ((xcd < rr) ? xcd * (qq + 1) : rr * (qq + 1) + (xcd - rr) * qq) + pos;
  const int m0 = (swz / nn) * BM;
  const int n0 = (swz % nn) * BN;

  const int wm = (wave >> 1) * (WM * 16), wn = (wave & 1) * (WN * 16);
  const int lr = lane & 15;
  const int lg = lane >> 4;

  auto stage = [&](int buf, int k0) {
#pragma unroll
    for (int i = 0; i < CHT / 256; ++i) {
      const int c = t + i * 256;
      if (c < CHA) {
        const int row = c >> 3, slot = c & 7;
        const int ca = slot ^ (row & 7);
        gload16(A + (size_t)(m0 + row) * K + k0 + ca * 8, &As[buf][c * 8]);
      } else {
        const int c2 = c - CHA, row = c2 >> 3, slot = c2 & 7;
        const int ca = slot ^ (row & 7);
        gload16(Bt + (size_t)(n0 + row) * K + k0 + ca * 8, &Bs[buf][c2 * 8]);
      }
    }
  };

  f32x4 acc[WM][WN] = {};

  stage(0, 0);
  __syncthreads();
  int cur = 0;

  for (int k0 = 0; k0 < K; k0 += 64) {
    if (k0 + 64 < K) stage(cur ^ 1, k0 + 64);   // prefetch next tile over compute

    bf16x8 af[2][WM], bg[2][WN];
#pragma unroll
    for (int kk = 0; kk < 2; ++kk) {
#pragma unroll
      for (int i = 0; i < WM; ++i) {
        const int row = wm + i * 16 + lr;
        const int slot = (kk * 4 + lg) ^ (row & 7);
        af[kk][i] = *(const bf16x8*)(&As[cur][row * 64 + slot * 8]);
      }
#pragma unroll
      for (int j = 0; j < WN; ++j) {
        const int row = wn + j * 16 + lr;
        const int slot = (kk * 4 + lg) ^ (row & 7);
        bg[kk][j] = *(const bf16x8*)(&Bs[cur][row * 64 + slot * 8]);
      }
    }
#pragma unroll
    for (int kk = 0; kk < 2; ++kk)
#pragma unroll
      for (int i = 0; i < WM; ++i)
#pragma unroll
        for (int j = 0; j < WN; ++j)
          acc[i][j] = __builtin_amdgcn_mfma_f32_16x16x32_bf16(af[kk][i], bg[kk][j], acc[i][j], 0, 0, 0);

    __syncthreads();   // drains vmcnt (next-tile staging) + protects buffer swap
    cur ^= 1;
  }

  const int orow = lg * 4;
  const float* addf = (const float*)add_;
  const unsigned short* addb = (const unsigned short*)add_;
  float* outf = (float*)out_;
  unsigned short* outb = (unsigned short*)out_;
#pragma unroll
  for (int i = 0; i < WM; ++i) {
#pragma unroll
    for (int j = 0; j < WN; ++j) {
      const int n = n0 + wn + j * 16 + lr;
      if (n < N) {
#pragma unroll
        for (int r = 0; r < 4; ++r) {
          const int m = m0 + wm + i * 16 + orow + r;
          if (m < M) {
            float v = acc[i][j][r] + bias[n];
            if (HAS_ADD) v += ADD_BF16 ? bf2f(addb[(size_t)m * N + n]) : addf[(size_t)m * N + n];
            if (OUT_BF16) outb[(size_t)m * N + n] = f2bf(v);
            else          outf[(size_t)m * N + n] = v;
          }
        }
      }
    }
  }
}

// ---------------- persistent weights-resident fc2: out = x + cout @ fc2W + fc2b
// K=192 fits: B-panel (128 cols x 192) staged into LDS ONCE (48KB, one barrier),
// then each block loops m-tiles with A held entirely in registers (12 b128
// loads/tile/wave) -> ZERO barriers in the loop; waves free-run. BW-bound op;
// fused bias + bf16 residual + fp32 store. Grid = 6 n-chunks x FCP blocks.
#define FCP 42
__global__ __launch_bounds__(512) void fc2_persist(const unsigned short* __restrict__ A,
                                                   const unsigned short* __restrict__ Bt,
                                                   const float* __restrict__ bias,
                                                   const unsigned short* __restrict__ add,
                                                   float* __restrict__ out, int M) {
  __shared__ unsigned short Bp[128 * 192];
  const int t = threadIdx.x;
  const int wave = t >> 6, lane = t & 63;
  const int lr = lane & 15, lg = lane >> 4;
  const int n0 = (blockIdx.x % 6) * 128;
  const int p  = blockIdx.x / 6;
  const int wm = (wave & 3) * 32, wn = (wave >> 2) * 64;

  // stage B panel once: 128 rows x 24 slots(16B) = 3072 chunks, 6/thread.
  // XOR (slot&7)^(row&7) within 8-slot blocks on BOTH source and read (rule #21).
#pragma unroll
  for (int i = 0; i < 6; ++i) {
    const int c = t + i * 512;
    const int row = c / 24, slot = c % 24;
    const int ca = (slot & ~7) | ((slot & 7) ^ (row & 7));
    gload16(Bt + (size_t)(n0 + row) * 192 + ca * 8, &Bp[c * 8]);
  }
  asm volatile("s_waitcnt vmcnt(0)" ::: "memory");
  __syncthreads();

  const int NTILE = M / 128;   // 189 exact
  for (int mt = p; mt < NTILE; mt += FCP) {
    const int m0 = mt * 128;
    bf16x8 a[2][6];
#pragma unroll
    for (int u = 0; u < 2; ++u) {
      const unsigned short* ap = A + (size_t)(m0 + wm + u * 16 + lr) * 192 + lg * 8;
#pragma unroll
      for (int ks = 0; ks < 6; ++ks) a[u][ks] = *(const bf16x8*)(ap + ks * 32);
    }
    f32x4 acc[2][4] = {};
#pragma unroll
    for (int ks = 0; ks < 6; ++ks) {
      bf16x8 bg[4];
#pragma unroll
      for (int j = 0; j < 4; ++j) {
        const int row = wn + j * 16 + lr;
        const int sp = ks * 4 + lg;
        const int slot = (sp & ~7) | ((sp & 7) ^ (row & 7));
        bg[j] = *(const bf16x8*)(&Bp[row * 192 + slot * 8]);
      }
#pragma unroll
      for (int u = 0; u < 2; ++u)
#pragma unroll
        for (int j = 0; j < 4; ++j)
          acc[u][j] = __builtin_amdgcn_mfma_f32_16x16x32_bf16(a[u][ks], bg[j], acc[u][j], 0, 0, 0);
    }
#pragma unroll
    for (int u = 0; u < 2; ++u)
#pragma unroll
      for (int j = 0; j < 4; ++j) {
        const int n = n0 + wn + j * 16 + lr;
#pragma unroll
        for (int r = 0; r < 4; ++r) {
          const int m = m0 + wm + u * 16 + lg * 4 + r;
          out[(size_t)m * DIMC + n] = acc[u][j][r] + bias[n] + bf2f(add[(size_t)m * DIMC + n]);
        }
      }
  }
}

// ---------------- deformable sampling: softmax(attw) + bilinear gather + NP-sum
__global__ __launch_bounds__(192) void deform_attn(const float* __restrict__ soaw,
                                                   const float* __restrict__ rp,
                                                   const float* __restrict__ value,
                                                   unsigned short* __restrict__ attn) {
  const int row = blockIdx.x;  // b*LQT + q
  const int b = row / LQT;
  const int t = threadIdx.x;
  const int h = t >> 5;
  const int l = t & 31;
  const float* sa = soaw + (size_t)row * 128;
  const float bx = rp[(size_t)row * 2 + 0] * (float)WW - 0.5f;
  const float by = rp[(size_t)row * 2 + 1] * (float)HH - 0.5f;

  float lg0 = sa[48 + h * 4 + 0], lg1 = sa[48 + h * 4 + 1];
  float lg2 = sa[48 + h * 4 + 2], lg3 = sa[48 + h * 4 + 3];
  float mx = fmaxf(fmaxf(lg0, lg1), fmaxf(lg2, lg3));
  float e0 = expf(lg0 - mx), e1 = expf(lg1 - mx), e2 = expf(lg2 - mx), e3 = expf(lg3 - mx);
  float inv = 1.0f / (e0 + e1 + e2 + e3);
  float awp[4] = {e0 * inv, e1 * inv, e2 * inv, e3 * inv};

  const float* vb = value + (size_t)b * LINT * DIMC + h * DHD + l * 4;
  float ax = 0.f, ay = 0.f, az = 0.f, aw = 0.f;
#pragma unroll
  for (int p = 0; p < 4; ++p) {
    float fx = bx + sa[h * 8 + p * 2 + 0];
    float fy = by + sa[h * 8 + p * 2 + 1];
    float x0f = floorf(fx), y0f = floorf(fy);
    float wx = fx - x0f, wy = fy - y0f;
    int x0 = (int)x0f, y0 = (int)y0f;
#pragma unroll
    for (int dy = 0; dy < 2; ++dy) {
#pragma unroll
      for (int dx = 0; dx < 2; ++dx) {
        int xi = x0 + dx, yi = y0 + dy;
        float w = (dy ? wy : 1.f - wy) * (dx ? wx : 1.f - wx) * awp[p];
        if (xi < 0 || xi >= WW || yi < 0 || yi >= HH) w = 0.f;
        int xc = min(max(xi, 0), WW - 1), yc = min(max(yi, 0), HH - 1);
        const float4 g = *(const float4*)(vb + (size_t)(yc * WW + xc) * DIMC);
        ax += w * g.x; ay += w * g.y; az += w * g.z; aw += w * g.w;
      }
    }
  }
  unsigned short* op = attn + (size_t)row * DIMC + h * DHD + l * 4;
  ushort4 ov;
  ov.x = f2bf(ax); ov.y = f2bf(ay); ov.z = f2bf(az); ov.w = f2bf(aw);
  *(ushort4*)op = ov;
}

// ---------------- depthwise 3x3 conv (3 image scales) + exact GELU, bf16 in/out
__global__ __launch_bounds__(192) void dwconv_gelu(const unsigned short* __restrict__ h1,
                                                   const float* __restrict__ dwW,
                                                   const float* __restrict__ dwb,
                                                   unsigned short* __restrict__ out) {
  const int blk = blockIdx.x;  // b*LQT + q
  const int b = blk / LQT;
  const int q = blk % LQT;
  int base, Wi, Hi;
  if (q < 9216)       { base = 0;     Wi = 96; Hi = 96; }
  else if (q < 11520) { base = 9216;  Wi = 48; Hi = 48; }
  else                { base = 11520; Wi = 24; Hi = 24; }
  const int loc = q - base;
  const int y = loc / Wi, x = loc % Wi;
  const int c = threadIdx.x;
  const unsigned short* src = h1 + ((size_t)b * LQT + base) * HIDC + c;
  float acc = dwb[c];
#pragma unroll
  for (int dy = -1; dy <= 1; ++dy) {
    int yy = y + dy;
    if (yy < 0 || yy >= Hi) continue;
#pragma unroll
    for (int dx = -1; dx <= 1; ++dx) {
      int xx = x + dx;
      if (xx < 0 || xx >= Wi) continue;
      acc += dwW[c * 9 + (dy + 1) * 3 + (dx + 1)] * bf2f(src[(size_t)(yy * Wi + xx) * HIDC]);
    }
  }
  float g = 0.5f * acc * (1.0f + erff(acc * 0.70710678118654752f));
  out[(size_t)blk * HIDC + c] = f2bf(g);
}

// ---------------- launch
extern "C" void kernel_launch(void* const* d_in, const int* in_sizes, int n_in,
                              void* d_out, int out_size, void* d_ws, size_t ws_size,
                              hipStream_t stream) {
  const float* query = (const float*)d_in[0];
  const float* rp    = (const float*)d_in[1];
  const float* feat  = (const float*)d_in[2];
  const float* qn_g  = (const float*)d_in[7];
  const float* qn_b  = (const float*)d_in[8];
  const float* fn_g  = (const float*)d_in[9];
  const float* fn_b  = (const float*)d_in[10];
  const float* mn_g  = (const float*)d_in[11];
  const float* mn_b  = (const float*)d_in[12];
  const float* vW    = (const float*)d_in[13];
  const float* vb    = (const float*)d_in[14];
  const float* soW   = (const float*)d_in[15];
  const float* sob   = (const float*)d_in[16];
  const float* awW   = (const float*)d_in[17];
  const float* awb   = (const float*)d_in[18];
  const float* opW   = (const float*)d_in[19];
  const float* opb   = (const float*)d_in[20];
  const float* fc1W  = (const float*)d_in[21];
  const float* fc1b  = (const float*)d_in[22];
  const float* dwW   = (const float*)d_in[23];
  const float* dwb   = (const float*)d_in[24];
  const float* fc2W  = (const float*)d_in[25];
  const float* fc2b  = (const float*)d_in[26];
  float* out = (float*)d_out;
  (void)in_sizes; (void)n_in; (void)out_size; (void)ws_size;

  char* ws = (char*)d_ws;
  size_t off = 0;
  auto alloc = [&](size_t bytes) -> void* {
    off = (off + 255) & ~(size_t)255;
    void* p = ws + off;
    off += bytes;
    return p;
  };

  const int MQ = NB * LQT;    // 24192 = 189*128
  const int MF = NB * LINT;   // 4608 = 36*128

  unsigned short* vWt    = (unsigned short*)alloc((size_t)768 * 768 * 2);
  unsigned short* opWt   = (unsigned short*)alloc((size_t)768 * 768 * 2);
  unsigned short* soawWt = (unsigned short*)alloc((size_t)128 * 768 * 2);
  unsigned short* fc1Wt  = (unsigned short*)alloc((size_t)192 * 768 * 2);
  unsigned short* fc2Wt  = (unsigned short*)alloc((size_t)768 * 192 * 2);
  float*          soawb  = (float*)alloc(128 * 4);
  unsigned short* f_ln   = (unsigned short*)alloc((size_t)MF * DIMC * 2);
  unsigned short* q_ln   = (unsigned short*)alloc((size_t)MQ * DIMC * 2);  // reused as ln(x)
  float*          value  = (float*)alloc((size_t)MF * DIMC * 4);
  float*          soaw   = (float*)alloc((size_t)MQ * 128 * 4);            // reused as conv out (bf16)
  unsigned short* attnb  = (unsigned short*)alloc((size_t)MQ * DIMC * 2);  // reused as h1 (bf16)
  unsigned short* xbuf   = (unsigned short*)alloc((size_t)MQ * DIMC * 2);  // x residual in bf16

  unsigned short* h1b = attnb;                   // fc1 output (bf16), after attnb consumed
  unsigned short* coutb = (unsigned short*)soaw; // MQ*192*2 = 9.3MB < 12.4MB
  unsigned short* lnx = q_ln;

  // weight packing (tiny)
  pack_wt<<<dim3((768 * 768 + 255) / 256), dim3(256), 0, stream>>>(vW, vWt, 768, 768, 768);
  pack_wt<<<dim3((768 * 768 + 255) / 256), dim3(256), 0, stream>>>(opW, opWt, 768, 768, 768);
  pack_wt<<<dim3((192 * 768 + 255) / 256), dim3(256), 0, stream>>>(fc1W, fc1Wt, 768, 192, 192);
  pack_wt<<<dim3((768 * 192 + 255) / 256), dim3(256), 0, stream>>>(fc2W, fc2Wt, 192, 768, 768);
  pack_soaw<<<dim3((128 * 768 + 255) / 256), dim3(256), 0, stream>>>(soW, awW, sob, awb, soawWt, soawb);

  // LayerNorms (fp32 in)
  ln_to_bf16<false><<<dim3(MF), dim3(256), 0, stream>>>(feat, fn_g, fn_b, f_ln);
  ln_to_bf16<false><<<dim3(MQ), dim3(256), 0, stream>>>(query, qn_g, qn_b, q_ln);

  // value projection: [4608,768] = f_ln @ vW + vb   (BM=64, grid 72x6)
  gemm_bt<2, 4, false, false, false><<<dim3((MF / 64) * 6), dim3(256), 0, stream>>>(
      f_ln, vWt, vb, nullptr, value, MF, 768, 768, 6);

  // sampling offsets + attn logits (N=128 padded; BM=64, grid 378)
  gemm_bt<2, 4, false, false, false><<<dim3(MQ / 64), dim3(256), 0, stream>>>(
      q_ln, soawWt, soawb, nullptr, soaw, MQ, 128, 768, 1);

  // deformable bilinear sampling -> attn operand (bf16)
  deform_attn<<<dim3(MQ), dim3(192), 0, stream>>>(soaw, rp, value, attnb);

  // output projection + residual: x = attn @ opW + opb + query  (128x128, bf16 out)
  gemm_bt<4, 4, true, false, true><<<dim3((MQ / 128) * 6), dim3(256), 0, stream>>>(
      attnb, opWt, opb, query, xbuf, MQ, 768, 768, 6);

  // LN(x) (bf16 in)
  ln_to_bf16<true><<<dim3(MQ), dim3(256), 0, stream>>>(xbuf, mn_g, mn_b, lnx);

  // fc1: h1 = lnx @ fc1W + fc1b  (BM=128, BN=64, grid 189x3, bf16 out)
  gemm_bt<4, 2, false, false, true><<<dim3((MQ / 128) * 3), dim3(256), 0, stream>>>(
      lnx, fc1Wt, fc1b, nullptr, h1b, MQ, 192, 768, 3);

  // depthwise conv (3 scales) + GELU (bf16 in/out)
  dwconv_gelu<<<dim3(MQ), dim3(192), 0, stream>>>(h1b, dwW, dwb, coutb);

  // fc2 + residual (persistent weights-resident, barrier-free loop)
  fc2_persist<<<dim3(6 * FCP), dim3(512), 0, stream>>>(coutb, fc2Wt, fc2b, xbuf, out, MQ);
}